// Round 2
// baseline (13429.349 us; speedup 1.0000x reference)
//
#include <hip/hip_runtime.h>
#include <math.h>

// Problem constants
#define B_SZ    4096
#define D_DIM   128
#define K_CODES 8192
#define RECON_N (4096*84*84)   // 28901376

// ============================ VQ argmin + losses ============================
// Exact emulation of numpy-f32 semantics:
//   d2 = fl32( fl32(zz + ee) - 2*r ) ; ee < ulp(zz)/2 is absorbed -> fl32(zz - 2r)
//   r  = f32 sequential FMA chain over d ascending (BLAS sgemm microkernel order)
//   zz = numpy pairwise-8 sum of fl32(z*z)
// argmin with ties -> lowest index (np.argmin first occurrence).
__global__ __launch_bounds__(256) void vq_kernel(
    const float* __restrict__ z, const float* __restrict__ cb,
    int* __restrict__ idx_ws, float* __restrict__ out_idx_f,
    double* __restrict__ lpart)
{
  __shared__ float z_s[16][128];
  __shared__ float e_s[64*129];     // stride 129: scalar reads (l+d)%32 -> 2-way (free)
  __shared__ float zz_s[16];
  __shared__ int win[16];
  __shared__ double wsum[4];
  const int t  = threadIdx.x;
  const int b0 = blockIdx.x * 16;

  for (int p = t; p < 16*128; p += 256) z_s[p >> 7][p & 127] = z[(size_t)b0*128 + p];
  __syncthreads();

  // numpy pairwise-8 emulation of (z*z).sum(axis=1); separate mul/add roundings
  if (t < 16) {
    #pragma clang fp contract(off)
    const float* a = z_s[t];
    float r8[8];
    #pragma unroll
    for (int j = 0; j < 8; j++) { float v = a[j]*a[j]; r8[j] = v; }
    for (int i = 8; i < 128; i += 8) {
      #pragma unroll
      for (int j = 0; j < 8; j++) { float v = a[i+j]*a[i+j]; r8[j] = r8[j] + v; }
    }
    zz_s[t] = ((r8[0]+r8[1]) + (r8[2]+r8[3])) + ((r8[4]+r8[5]) + (r8[6]+r8[7]));
  }
  __syncthreads();

  const int lane = t & 63, wv = t >> 6;
  const float* zr0 = z_s[wv*4 + 0];
  const float* zr1 = z_s[wv*4 + 1];
  const float* zr2 = z_s[wv*4 + 2];
  const float* zr3 = z_s[wv*4 + 3];
  const float zz0 = zz_s[wv*4 + 0];
  const float zz1 = zz_s[wv*4 + 1];
  const float zz2 = zz_s[wv*4 + 2];
  const float zz3 = zz_s[wv*4 + 3];

  float best0 = INFINITY, best1 = INFINITY, best2 = INFINITY, best3 = INFINITY;
  int bi0 = 0, bi1 = 0, bi2 = 0, bi3 = 0;

  for (int ch = 0; ch < K_CODES/64; ch++) {
    __syncthreads();
    const float4* src = (const float4*)(cb + (size_t)ch*64*128);
    for (int q = t; q < 64*32; q += 256) {
      float4 v = src[q];
      float* dst = &e_s[(q >> 5)*129 + (q & 31)*4];
      dst[0] = v.x; dst[1] = v.y; dst[2] = v.z; dst[3] = v.w;
    }
    __syncthreads();
    const float* e = &e_s[lane*129];
    float r0 = 0.f, r1 = 0.f, r2 = 0.f, r3 = 0.f;
    #pragma unroll
    for (int d = 0; d < 128; d += 4) {
      const float4 a0 = *(const float4*)(zr0 + d);   // wave-uniform -> LDS broadcast
      const float4 a1 = *(const float4*)(zr1 + d);
      const float4 a2 = *(const float4*)(zr2 + d);
      const float4 a3 = *(const float4*)(zr3 + d);
      const float e0 = e[d], e1 = e[d+1], e2 = e[d+2], e3 = e[d+3];
      // single dependent FMA chain per (row,code), d ascending — BLAS order
      r0 = fmaf(a0.x,e0,r0); r0 = fmaf(a0.y,e1,r0); r0 = fmaf(a0.z,e2,r0); r0 = fmaf(a0.w,e3,r0);
      r1 = fmaf(a1.x,e0,r1); r1 = fmaf(a1.y,e1,r1); r1 = fmaf(a1.z,e2,r1); r1 = fmaf(a1.w,e3,r1);
      r2 = fmaf(a2.x,e0,r2); r2 = fmaf(a2.y,e1,r2); r2 = fmaf(a2.z,e2,r2); r2 = fmaf(a2.w,e3,r2);
      r3 = fmaf(a3.x,e0,r3); r3 = fmaf(a3.y,e1,r3); r3 = fmaf(a3.z,e2,r3); r3 = fmaf(a3.w,e3,r3);
    }
    const int c = ch*64 + lane;
    // d2q = fl32(zz - 2r): exact doubling -> fmaf gives identical single rounding
    float t0 = fmaf(-2.0f, r0, zz0); if (t0 < best0) { best0 = t0; bi0 = c; }
    float t1 = fmaf(-2.0f, r1, zz1); if (t1 < best1) { best1 = t1; bi1 = c; }
    float t2 = fmaf(-2.0f, r2, zz2); if (t2 < best2) { best2 = t2; bi2 = c; }
    float t3 = fmaf(-2.0f, r3, zz3); if (t3 < best3) { best3 = t3; bi3 = c; }
  }

  // cross-lane argmin (tie -> smaller index = np.argmin first occurrence)
  float bv[4] = {best0, best1, best2, best3};
  int   bi[4] = {bi0, bi1, bi2, bi3};
  #pragma unroll
  for (int r = 0; r < 4; r++) {
    float v = bv[r]; int i = bi[r];
    #pragma unroll
    for (int m = 32; m; m >>= 1) {
      float v2 = __shfl_xor(v, m, 64);
      int   i2 = __shfl_xor(i, m, 64);
      if (v2 < v || (v2 == v && i2 < i)) { v = v2; i = i2; }
    }
    if (lane == 0) win[wv*4 + r] = i;
  }
  __syncthreads();

  // loss partial: sum (z - e_win)^2 over this block's 16 rows (f64; thr ~2%)
  double ls = 0.0;
  for (int f = t; f < 2048; f += 256) {
    int r = f >> 7, d = f & 127;
    float diff = z_s[r][d] - cb[(size_t)win[r]*128 + d];
    ls = fma((double)diff, (double)diff, ls);
  }
  #pragma unroll
  for (int m = 32; m; m >>= 1) ls += __shfl_xor(ls, m, 64);
  if (lane == 0) wsum[wv] = ls;
  __syncthreads();
  if (t == 0) lpart[blockIdx.x] = wsum[0] + wsum[1] + wsum[2] + wsum[3];
  if (t < 16) {
    idx_ws[b0 + t] = win[t];
    out_idx_f[b0 + t] = (float)win[t];   // out buffer is float32; exact for idx<2^24
  }
}

__global__ __launch_bounds__(256) void fin_kernel(const double* __restrict__ lpart,
                                                  float* __restrict__ out_loss)
{
  __shared__ double s[256];
  const int t = threadIdx.x;
  s[t] = lpart[t];
  __syncthreads();
  for (int off = 128; off; off >>= 1) {
    if (t < off) s[t] += s[t + off];
    __syncthreads();
  }
  if (t == 0) {
    float l = (float)(s[0] / (4096.0*128.0));
    out_loss[0] = l;   // codebook_loss
    out_loss[1] = l;   // commitment_loss (same value)
  }
}

// ===================== linear: x1[b,o] = cb[idx[b]] . lin_w[o] + lin_b[o] ====
// 64x64 output tile, K=128 in two 64-chunks; 256 threads, 4x4 microtile.
__global__ __launch_bounds__(256) void linear_kernel(
    const float* __restrict__ cb, const int* __restrict__ idx,
    const float* __restrict__ lw, const float* __restrict__ lb,
    float* __restrict__ x1)
{
  __shared__ float As[64][65];
  __shared__ float Bs[64][65];
  __shared__ int idx_s[64];
  const int t  = threadIdx.x;
  const int b0 = blockIdx.x * 64, n0 = blockIdx.y * 64;
  if (t < 64) idx_s[t] = idx[b0 + t];
  float acc[4][4] = {{0.f}};
  const int tr = (t >> 4)*4, tc = (t & 15)*4;
  for (int d0 = 0; d0 < 128; d0 += 64) {
    __syncthreads();   // also covers idx_s on first iteration
    #pragma unroll
    for (int l = 0; l < 16; l++) {
      int flat = t + l*256;
      int r = flat >> 6, d = flat & 63;
      As[r][d] = cb[(size_t)idx_s[r]*128 + d0 + d];
      Bs[r][d] = lw[(size_t)(n0 + r)*128 + d0 + d];
    }
    __syncthreads();
    #pragma unroll 8
    for (int d = 0; d < 64; d++) {
      float a0 = As[tr+0][d], a1 = As[tr+1][d], a2 = As[tr+2][d], a3 = As[tr+3][d];
      float q0 = Bs[tc+0][d], q1 = Bs[tc+1][d], q2 = Bs[tc+2][d], q3 = Bs[tc+3][d];
      acc[0][0] = fmaf(a0,q0,acc[0][0]); acc[0][1] = fmaf(a0,q1,acc[0][1]);
      acc[0][2] = fmaf(a0,q2,acc[0][2]); acc[0][3] = fmaf(a0,q3,acc[0][3]);
      acc[1][0] = fmaf(a1,q0,acc[1][0]); acc[1][1] = fmaf(a1,q1,acc[1][1]);
      acc[1][2] = fmaf(a1,q2,acc[1][2]); acc[1][3] = fmaf(a1,q3,acc[1][3]);
      acc[2][0] = fmaf(a2,q0,acc[2][0]); acc[2][1] = fmaf(a2,q1,acc[2][1]);
      acc[2][2] = fmaf(a2,q2,acc[2][2]); acc[2][3] = fmaf(a2,q3,acc[2][3]);
      acc[3][0] = fmaf(a3,q0,acc[3][0]); acc[3][1] = fmaf(a3,q1,acc[3][1]);
      acc[3][2] = fmaf(a3,q2,acc[3][2]); acc[3][3] = fmaf(a3,q3,acc[3][3]);
    }
  }
  #pragma unroll
  for (int i = 0; i < 4; i++)
    #pragma unroll
    for (int j = 0; j < 4; j++)
      x1[(size_t)(b0 + tr + i)*3136 + n0 + tc + j] = acc[i][j] + lb[n0 + tc + j];
}

// =========================== fused per-image decoder ========================
// One block per image. All activations resident in LDS:
//   Xs  3136 f            (x1 image; later overlaid by WB2/W3s)
//   B1s 64*197 = 12608 f  (conv1 out, padded stride; later overlaid by Ds)
//   C2s 32*785 = 25120 f  (conv2 out, padded stride; WB1 overlay during conv1)
// Total 40864 floats = 163456 B dynamic LDS.
#define DEC_T 896
__global__ __launch_bounds__(DEC_T, 1) void decoder_kernel(
    const float* __restrict__ x1,
    const float* __restrict__ w1, const float* __restrict__ b1,
    const float* __restrict__ w2, const float* __restrict__ b2,
    const float* __restrict__ w3, const float* __restrict__ b3,
    float* __restrict__ out)
{
  extern __shared__ float lds[];
  float* Xs  = lds;                 // 3136
  float* B1s = lds + 3136;          // 12608
  float* C2s = lds + 3136 + 12608;  // 25120
  float* WB1 = C2s;                 // conv1 weight staging (8704 f used)
  float* WB2 = Xs;                  // conv2 weight staging (2176 f used)
  float* W3s = Xs;                  // conv3 weights (512 f)
  float* Ds  = B1s;                 // conv3 out (3136 f)

  const int tid = threadIdx.x;
  const int b   = blockIdx.x;

  for (int p = tid; p < 3136; p += DEC_T) Xs[p] = x1[(size_t)b*3136 + p];

  // ---- conv1: (64,7,7) -> (64,14,14), relu. thread = (c=tid&63, y=tid>>6) ----
  {
    const int c = tid & 63, y = tid >> 6;
    const int ky0 = (y & 1) ? 0 : 1;
    const int iy0 = (y + 1 - ky0) >> 1;   // row for ky0   (valid if <7)
    const int iy1 = iy0 - 1;              // row for ky0+2 (valid if >=0)
    const bool v0 = (iy0 < 7), v1 = (iy1 >= 0);
    float acc[14];
    const float bias = b1[c];
    #pragma unroll
    for (int x = 0; x < 14; x++) acc[x] = bias;
    for (int i0 = 0; i0 < 64; i0 += 8) {
      __syncthreads();
      for (int p = tid; p < 8192; p += DEC_T)
        WB1[(p >> 4)*17 + (p & 15)] = w1[i0*1024 + p];   // [i][c] stride 17: no bank conflict
      __syncthreads();
      #pragma unroll
      for (int ii = 0; ii < 8; ii++) {
        const int i = i0 + ii;
        const float* wr = &WB1[(ii*64 + c)*17];
        float wA[4], wB[4];
        #pragma unroll
        for (int k = 0; k < 4; k++) { wA[k] = wr[ky0*4 + k]; wB[k] = wr[(ky0+2)*4 + k]; }
        const float* Xi = &Xs[i*49];
        float r0[7], r1[7];
        #pragma unroll
        for (int j = 0; j < 7; j++) {
          r0[j] = v0 ? Xi[iy0*7 + j] : 0.0f;
          r1[j] = v1 ? Xi[iy1*7 + j] : 0.0f;
        }
        #pragma unroll
        for (int x = 0; x < 14; x++) {
          const int kxs = (x & 1) ? 0 : 1;
          const int ix0 = (x + 1 - kxs) >> 1;
          const int ix1 = ix0 - 1;
          float s = acc[x];
          if (ix0 < 7)  { s = fmaf(r0[ix0], wA[kxs],   s); s = fmaf(r1[ix0], wB[kxs],   s); }
          if (ix1 >= 0) { s = fmaf(r0[ix1], wA[kxs+2], s); s = fmaf(r1[ix1], wB[kxs+2], s); }
          acc[x] = s;
        }
      }
    }
    float* o = &B1s[c*197 + y*14];
    #pragma unroll
    for (int x = 0; x < 14; x++) o[x] = fmaxf(acc[x], 0.0f);
  }
  __syncthreads();

  // ---- conv2: (64,14,14) -> (32,28,28), relu. thread = (c=tid&31, y=tid>>5) ----
  {
    const int c = tid & 31, y = tid >> 5;
    const int ky0 = (y & 1) ? 0 : 1;
    const int iy0 = (y + 1 - ky0) >> 1;   // valid if <14
    const int iy1 = iy0 - 1;              // valid if >=0
    const bool v0 = (iy0 < 14), v1 = (iy1 >= 0);
    float acc[28];
    const float bias = b2[c];
    #pragma unroll
    for (int x = 0; x < 28; x++) acc[x] = bias;
    for (int i0 = 0; i0 < 64; i0 += 4) {
      __syncthreads();
      for (int p = tid; p < 2048; p += DEC_T)
        WB2[(p >> 4)*17 + (p & 15)] = w2[i0*512 + p];
      __syncthreads();
      #pragma unroll
      for (int ii = 0; ii < 4; ii++) {
        const int i = i0 + ii;
        const float* wr = &WB2[(ii*32 + c)*17];
        float wA[4], wB[4];
        #pragma unroll
        for (int k = 0; k < 4; k++) { wA[k] = wr[ky0*4 + k]; wB[k] = wr[(ky0+2)*4 + k]; }
        const float* Bi = &B1s[i*197];
        float r0[14], r1[14];
        #pragma unroll
        for (int j = 0; j < 14; j++) {
          r0[j] = v0 ? Bi[iy0*14 + j] : 0.0f;
          r1[j] = v1 ? Bi[iy1*14 + j] : 0.0f;
        }
        #pragma unroll
        for (int x = 0; x < 28; x++) {
          const int kxs = (x & 1) ? 0 : 1;
          const int ix0 = (x + 1 - kxs) >> 1;
          const int ix1 = ix0 - 1;
          float s = acc[x];
          if (ix0 < 14) { s = fmaf(r0[ix0], wA[kxs],   s); s = fmaf(r1[ix0], wB[kxs],   s); }
          if (ix1 >= 0) { s = fmaf(r0[ix1], wA[kxs+2], s); s = fmaf(r1[ix1], wB[kxs+2], s); }
          acc[x] = s;
        }
      }
    }
    float* o = &C2s[c*785 + y*28];
    #pragma unroll
    for (int x = 0; x < 28; x++) o[x] = fmaxf(acc[x], 0.0f);
  }
  __syncthreads();

  // ---- conv3: (32,28,28) -> (1,56,56), no relu. thread = (y=tid>>1, half=tid&1) ----
  for (int p = tid; p < 512; p += DEC_T) W3s[p] = w3[p];
  __syncthreads();
  if (tid < 112) {
    const int y = tid >> 1, h = tid & 1;
    const int x0 = h*28;
    const int ky0 = (y & 1) ? 0 : 1;
    const int iy0 = (y + 1 - ky0) >> 1;   // valid if <28
    const int iy1 = iy0 - 1;              // valid if >=0
    const bool v0 = (iy0 < 28), v1 = (iy1 >= 0);
    const int ixb = h*14 - 1;
    float acc[28];
    const float bias = b3[0];
    #pragma unroll
    for (int x = 0; x < 28; x++) acc[x] = bias;
    for (int i = 0; i < 32; i++) {
      const float* wr = &W3s[i*16];
      float wA[4], wB[4];
      #pragma unroll
      for (int k = 0; k < 4; k++) { wA[k] = wr[ky0*4 + k]; wB[k] = wr[(ky0+2)*4 + k]; }
      const float* Ci = &C2s[i*785];
      float r0[16], r1[16];
      #pragma unroll
      for (int j = 0; j < 16; j++) {
        const int ix = ixb + j;
        const bool vx = (ix >= 0) && (ix < 28);
        r0[j] = (v0 && vx) ? Ci[iy0*28 + ix] : 0.0f;
        r1[j] = (v1 && vx) ? Ci[iy1*28 + ix] : 0.0f;
      }
      #pragma unroll
      for (int xl = 0; xl < 28; xl++) {
        const int kxs = (xl & 1) ? 0 : 1;
        const int j0 = ((xl + 1 - kxs) >> 1) + 1;
        const int j1 = j0 - 1;
        float s = acc[xl];
        s = fmaf(r0[j0], wA[kxs],   s);
        s = fmaf(r1[j0], wB[kxs],   s);
        s = fmaf(r0[j1], wA[kxs+2], s);
        s = fmaf(r1[j1], wB[kxs+2], s);
        acc[xl] = s;
      }
    }
    float* o = &Ds[y*56 + x0];
    #pragma unroll
    for (int xl = 0; xl < 28; xl++) o[xl] = acc[xl];
  }
  __syncthreads();

  // ---- bilinear resize 56->84 (half-pixel, edge clamp == jax renormalized) + tanh ----
  for (int p = tid; p < 84*84; p += DEC_T) {
    const int oy = p / 84, ox = p - oy*84;
    const float sy = (oy + 0.5f)*(2.0f/3.0f) - 0.5f;
    const float sx = (ox + 0.5f)*(2.0f/3.0f) - 0.5f;
    const int y0 = (int)floorf(sy), x0i = (int)floorf(sx);
    const float fy = sy - (float)y0, fx = sx - (float)x0i;
    const int y0c = y0 < 0 ? 0 : y0, y1c = (y0 + 1 > 55) ? 55 : (y0 + 1);
    const int x0c = x0i < 0 ? 0 : x0i, x1c = (x0i + 1 > 55) ? 55 : (x0i + 1);
    const float v00 = Ds[y0c*56 + x0c], v01 = Ds[y0c*56 + x1c];
    const float v10 = Ds[y1c*56 + x0c], v11 = Ds[y1c*56 + x1c];
    const float v = (v00*(1.0f - fx) + v01*fx)*(1.0f - fy)
                  + (v10*(1.0f - fx) + v11*fx)*fy;
    out[(size_t)b*7056 + p] = tanhf(v);
  }
}

// ================================ launch ====================================
extern "C" void kernel_launch(void* const* d_in, const int* in_sizes, int n_in,
                              void* d_out, int out_size, void* d_ws, size_t ws_size,
                              hipStream_t stream) {
  (void)in_sizes; (void)n_in; (void)out_size; (void)ws_size;
  const float* z  = (const float*)d_in[0];
  const float* cb = (const float*)d_in[1];
  const float* lw = (const float*)d_in[2];
  const float* lb = (const float*)d_in[3];
  const float* w1 = (const float*)d_in[4];
  const float* b1 = (const float*)d_in[5];
  const float* w2 = (const float*)d_in[6];
  const float* b2 = (const float*)d_in[7];
  const float* w3 = (const float*)d_in[8];
  const float* b3 = (const float*)d_in[9];

  float* out      = (float*)d_out;
  float* out_idx  = out + RECON_N;          // 4096 indices as float
  float* out_loss = out + RECON_N + 4096;   // 2 losses

  char*   ws     = (char*)d_ws;
  double* lpart  = (double*)ws;             // 256 doubles
  int*    idx_ws = (int*)(ws + 2048);       // 4096 ints
  float*  x1     = (float*)(ws + 18432);    // 4096*3136 floats (51.4 MB)

  vq_kernel<<<256, 256, 0, stream>>>(z, cb, idx_ws, out_idx, lpart);
  fin_kernel<<<1, 256, 0, stream>>>(lpart, out_loss);
  linear_kernel<<<dim3(64, 49), 256, 0, stream>>>(cb, idx_ws, lw, lb, x1);

  const int dec_lds = (3136 + 12608 + 25120) * 4;   // 163456 B
  hipFuncSetAttribute((const void*)decoder_kernel,
                      hipFuncAttributeMaxDynamicSharedMemorySize, dec_lds);
  decoder_kernel<<<4096, DEC_T, dec_lds, stream>>>(x1, w1, b1, w2, b2, w3, b3, out);
}

// Round 3
// 2937.998 us; speedup vs baseline: 4.5709x; 4.5709x over previous
//
#include <hip/hip_runtime.h>
#include <math.h>

// Problem constants
#define B_SZ    4096
#define D_DIM   128
#define K_CODES 8192
#define RECON_N (4096*84*84)   // 28901376

// ============================ VQ argmin + losses ============================
// Exact emulation of numpy-f32 semantics:
//   d2 = fl32( fl32(zz + ee) - 2*r ) ; ee < ulp(zz)/2 is absorbed -> fl32(zz - 2r)
//   r  = f32 sequential FMA chain over d ascending (BLAS sgemm microkernel order)
//   zz = numpy pairwise-8 sum of fl32(z*z)
// argmin with ties -> lowest index (np.argmin first occurrence).
__global__ __launch_bounds__(256) void vq_kernel(
    const float* __restrict__ z, const float* __restrict__ cb,
    int* __restrict__ idx_ws, float* __restrict__ out_idx_f,
    double* __restrict__ lpart)
{
  __shared__ float z_s[16][128];
  __shared__ float e_s[64*129];     // stride 129: scalar reads -> 2-way (free)
  __shared__ float zz_s[16];
  __shared__ int win[16];
  __shared__ double wsum[4];
  const int t  = threadIdx.x;
  const int b0 = blockIdx.x * 16;

  for (int p = t; p < 16*128; p += 256) z_s[p >> 7][p & 127] = z[(size_t)b0*128 + p];
  __syncthreads();

  // numpy pairwise-8 emulation of (z*z).sum(axis=1); separate mul/add roundings
  if (t < 16) {
    #pragma clang fp contract(off)
    const float* a = z_s[t];
    float r8[8];
    #pragma unroll
    for (int j = 0; j < 8; j++) { float v = a[j]*a[j]; r8[j] = v; }
    for (int i = 8; i < 128; i += 8) {
      #pragma unroll
      for (int j = 0; j < 8; j++) { float v = a[i+j]*a[i+j]; r8[j] = r8[j] + v; }
    }
    zz_s[t] = ((r8[0]+r8[1]) + (r8[2]+r8[3])) + ((r8[4]+r8[5]) + (r8[6]+r8[7]));
  }
  __syncthreads();

  const int lane = t & 63, wv = t >> 6;
  const float* zr0 = z_s[wv*4 + 0];
  const float* zr1 = z_s[wv*4 + 1];
  const float* zr2 = z_s[wv*4 + 2];
  const float* zr3 = z_s[wv*4 + 3];
  const float zz0 = zz_s[wv*4 + 0];
  const float zz1 = zz_s[wv*4 + 1];
  const float zz2 = zz_s[wv*4 + 2];
  const float zz3 = zz_s[wv*4 + 3];

  float best0 = INFINITY, best1 = INFINITY, best2 = INFINITY, best3 = INFINITY;
  int bi0 = 0, bi1 = 0, bi2 = 0, bi3 = 0;

  for (int ch = 0; ch < K_CODES/64; ch++) {
    __syncthreads();
    const float4* src = (const float4*)(cb + (size_t)ch*64*128);
    for (int q = t; q < 64*32; q += 256) {
      float4 v = src[q];
      float* dst = &e_s[(q >> 5)*129 + (q & 31)*4];
      dst[0] = v.x; dst[1] = v.y; dst[2] = v.z; dst[3] = v.w;
    }
    __syncthreads();
    const float* e = &e_s[lane*129];
    float r0 = 0.f, r1 = 0.f, r2 = 0.f, r3 = 0.f;
    #pragma unroll
    for (int d = 0; d < 128; d += 4) {
      const float4 a0 = *(const float4*)(zr0 + d);   // wave-uniform -> LDS broadcast
      const float4 a1 = *(const float4*)(zr1 + d);
      const float4 a2 = *(const float4*)(zr2 + d);
      const float4 a3 = *(const float4*)(zr3 + d);
      const float e0 = e[d], e1 = e[d+1], e2 = e[d+2], e3 = e[d+3];
      // single dependent FMA chain per (row,code), d ascending — BLAS order
      r0 = fmaf(a0.x,e0,r0); r0 = fmaf(a0.y,e1,r0); r0 = fmaf(a0.z,e2,r0); r0 = fmaf(a0.w,e3,r0);
      r1 = fmaf(a1.x,e0,r1); r1 = fmaf(a1.y,e1,r1); r1 = fmaf(a1.z,e2,r1); r1 = fmaf(a1.w,e3,r1);
      r2 = fmaf(a2.x,e0,r2); r2 = fmaf(a2.y,e1,r2); r2 = fmaf(a2.z,e2,r2); r2 = fmaf(a2.w,e3,r2);
      r3 = fmaf(a3.x,e0,r3); r3 = fmaf(a3.y,e1,r3); r3 = fmaf(a3.z,e2,r3); r3 = fmaf(a3.w,e3,r3);
    }
    const int c = ch*64 + lane;
    // d2q = fl32(zz - 2r): exact doubling -> fmaf gives identical single rounding
    float t0 = fmaf(-2.0f, r0, zz0); if (t0 < best0) { best0 = t0; bi0 = c; }
    float t1 = fmaf(-2.0f, r1, zz1); if (t1 < best1) { best1 = t1; bi1 = c; }
    float t2 = fmaf(-2.0f, r2, zz2); if (t2 < best2) { best2 = t2; bi2 = c; }
    float t3 = fmaf(-2.0f, r3, zz3); if (t3 < best3) { best3 = t3; bi3 = c; }
  }

  // cross-lane argmin (tie -> smaller index = np.argmin first occurrence)
  float bv[4] = {best0, best1, best2, best3};
  int   bi[4] = {bi0, bi1, bi2, bi3};
  #pragma unroll
  for (int r = 0; r < 4; r++) {
    float v = bv[r]; int i = bi[r];
    #pragma unroll
    for (int m = 32; m; m >>= 1) {
      float v2 = __shfl_xor(v, m, 64);
      int   i2 = __shfl_xor(i, m, 64);
      if (v2 < v || (v2 == v && i2 < i)) { v = v2; i = i2; }
    }
    if (lane == 0) win[wv*4 + r] = i;
  }
  __syncthreads();

  // loss partial: sum (z - e_win)^2 over this block's 16 rows (f64; thr ~2%)
  double ls = 0.0;
  for (int f = t; f < 2048; f += 256) {
    int r = f >> 7, d = f & 127;
    float diff = z_s[r][d] - cb[(size_t)win[r]*128 + d];
    ls = fma((double)diff, (double)diff, ls);
  }
  #pragma unroll
  for (int m = 32; m; m >>= 1) ls += __shfl_xor(ls, m, 64);
  if (lane == 0) wsum[wv] = ls;
  __syncthreads();
  if (t == 0) lpart[blockIdx.x] = wsum[0] + wsum[1] + wsum[2] + wsum[3];
  if (t < 16) {
    idx_ws[b0 + t] = win[t];
    out_idx_f[b0 + t] = (float)win[t];   // out buffer is float32; exact for idx<2^24
  }
}

__global__ __launch_bounds__(256) void fin_kernel(const double* __restrict__ lpart,
                                                  float* __restrict__ out_loss)
{
  __shared__ double s[256];
  const int t = threadIdx.x;
  s[t] = lpart[t];
  __syncthreads();
  for (int off = 128; off; off >>= 1) {
    if (t < off) s[t] += s[t + off];
    __syncthreads();
  }
  if (t == 0) {
    float l = (float)(s[0] / (4096.0*128.0));
    out_loss[0] = l;   // codebook_loss
    out_loss[1] = l;   // commitment_loss (same value)
  }
}

// ===================== linear: x1[b,o] = cb[idx[b]] . lin_w[o] + lin_b[o] ====
__global__ __launch_bounds__(256) void linear_kernel(
    const float* __restrict__ cb, const int* __restrict__ idx,
    const float* __restrict__ lw, const float* __restrict__ lb,
    float* __restrict__ x1)
{
  __shared__ float As[64][65];
  __shared__ float Bs[64][65];
  __shared__ int idx_s[64];
  const int t  = threadIdx.x;
  const int b0 = blockIdx.x * 64, n0 = blockIdx.y * 64;
  if (t < 64) idx_s[t] = idx[b0 + t];
  float acc[4][4] = {{0.f}};
  const int tr = (t >> 4)*4, tc = (t & 15)*4;
  for (int d0 = 0; d0 < 128; d0 += 64) {
    __syncthreads();   // also covers idx_s on first iteration
    #pragma unroll
    for (int l = 0; l < 16; l++) {
      int flat = t + l*256;
      int r = flat >> 6, d = flat & 63;
      As[r][d] = cb[(size_t)idx_s[r]*128 + d0 + d];
      Bs[r][d] = lw[(size_t)(n0 + r)*128 + d0 + d];
    }
    __syncthreads();
    #pragma unroll 8
    for (int d = 0; d < 64; d++) {
      float a0 = As[tr+0][d], a1 = As[tr+1][d], a2 = As[tr+2][d], a3 = As[tr+3][d];
      float q0 = Bs[tc+0][d], q1 = Bs[tc+1][d], q2 = Bs[tc+2][d], q3 = Bs[tc+3][d];
      acc[0][0] = fmaf(a0,q0,acc[0][0]); acc[0][1] = fmaf(a0,q1,acc[0][1]);
      acc[0][2] = fmaf(a0,q2,acc[0][2]); acc[0][3] = fmaf(a0,q3,acc[0][3]);
      acc[1][0] = fmaf(a1,q0,acc[1][0]); acc[1][1] = fmaf(a1,q1,acc[1][1]);
      acc[1][2] = fmaf(a1,q2,acc[1][2]); acc[1][3] = fmaf(a1,q3,acc[1][3]);
      acc[2][0] = fmaf(a2,q0,acc[2][0]); acc[2][1] = fmaf(a2,q1,acc[2][1]);
      acc[2][2] = fmaf(a2,q2,acc[2][2]); acc[2][3] = fmaf(a2,q3,acc[2][3]);
      acc[3][0] = fmaf(a3,q0,acc[3][0]); acc[3][1] = fmaf(a3,q1,acc[3][1]);
      acc[3][2] = fmaf(a3,q2,acc[3][2]); acc[3][3] = fmaf(a3,q3,acc[3][3]);
    }
  }
  #pragma unroll
  for (int i = 0; i < 4; i++)
    #pragma unroll
    for (int j = 0; j < 4; j++)
      x1[(size_t)(b0 + tr + i)*3136 + n0 + tc + j] = acc[i][j] + lb[n0 + tc + j];
}

// =========================== fused per-image decoder ========================
// One block per image; all activations in LDS (40864 f = 163456 B dynamic).
// KEY FIX vs R2: dynamic LDS hides the 1-block/CU occupancy from the compiler,
// whose default 8-waves/EU target capped VGPR at 64 and spilled ~49 GB/launch
// to scratch. 14 waves/block @ 1 block/CU => 4 waves/EU is the true ceiling:
// pin it (VGPR budget 128) and keep live pressure < 128 via unroll-1 c_in loops.
#define DEC_T 896
__global__ __attribute__((amdgpu_flat_work_group_size(DEC_T, DEC_T),
                          amdgpu_waves_per_eu(4, 4)))
void decoder_kernel(
    const float* __restrict__ x1,
    const float* __restrict__ w1, const float* __restrict__ b1,
    const float* __restrict__ w2, const float* __restrict__ b2,
    const float* __restrict__ w3, const float* __restrict__ b3,
    float* __restrict__ out)
{
  extern __shared__ float lds[];
  float* Xs  = lds;                 // 3136
  float* B1s = lds + 3136;          // 64*197 = 12608 (stride 197: write conflict-free)
  float* C2s = lds + 15744;         // 32*785 = 25120 (stride 785: write conflict-free)
  float* WB1 = C2s;                 // conv1 weight staging overlay (8704 f)
  float* WB2 = Xs;                  // conv2 weight staging overlay (2176 f)
  float* W3s = Xs;                  // conv3 weights (512 f)
  float* Ds  = B1s;                 // conv3 out (3136 f)

  const int tid = threadIdx.x;
  const int b   = blockIdx.x;

  {
    const float4* src = (const float4*)(x1 + (size_t)b*3136);
    for (int p = tid; p < 784; p += DEC_T) ((float4*)Xs)[p] = src[p];
  }

  // ---- conv1: (64,7,7) -> (64,14,14), relu. item = (c=tid&63, y=tid>>6) ----
  {
    const int c = tid & 63, y = tid >> 6;
    const int ky0 = (y & 1) ? 0 : 1;
    const int iy0 = (y + 1 - ky0) >> 1;   // row for ky0   (valid if <7)
    const int iy1 = iy0 - 1;              // row for ky0+2 (valid if >=0)
    const bool v0 = (iy0 < 7), v1 = (iy1 >= 0);
    float acc[14];
    const float bias = b1[c];
    #pragma unroll
    for (int x = 0; x < 14; x++) acc[x] = bias;
    for (int i0 = 0; i0 < 64; i0 += 8) {
      __syncthreads();
      for (int p = tid; p < 8192; p += DEC_T)
        WB1[(p >> 4)*17 + (p & 15)] = w1[i0*1024 + p];   // [i][c] stride 17
      __syncthreads();
      #pragma unroll 1
      for (int ii = 0; ii < 8; ii++) {
        const int i = i0 + ii;
        const float* wr = &WB1[(ii*64 + c)*17];
        float wA[4], wB[4];
        #pragma unroll
        for (int k = 0; k < 4; k++) { wA[k] = wr[ky0*4 + k]; wB[k] = wr[(ky0+2)*4 + k]; }
        const float* Xi = &Xs[i*49];
        float r0[7], r1[7];
        #pragma unroll
        for (int j = 0; j < 7; j++) {
          r0[j] = v0 ? Xi[iy0*7 + j] : 0.0f;
          r1[j] = v1 ? Xi[iy1*7 + j] : 0.0f;
        }
        #pragma unroll
        for (int x = 0; x < 14; x++) {
          const int kxs = (x & 1) ? 0 : 1;
          const int ix0 = (x + 1 - kxs) >> 1;
          const int ix1 = ix0 - 1;
          float s = acc[x];
          if (ix0 < 7)  { s = fmaf(r0[ix0], wA[kxs],   s); s = fmaf(r1[ix0], wB[kxs],   s); }
          if (ix1 >= 0) { s = fmaf(r0[ix1], wA[kxs+2], s); s = fmaf(r1[ix1], wB[kxs+2], s); }
          acc[x] = s;
        }
      }
    }
    float* o = &B1s[c*197 + y*14];
    #pragma unroll
    for (int x = 0; x < 14; x++) o[x] = fmaxf(acc[x], 0.0f);
  }
  __syncthreads();

  // ---- conv2: (64,14,14) -> (32,28,28), relu. item = (c=tid&31, y=tid>>5) ----
  {
    const int c = tid & 31, y = tid >> 5;
    const int ky0 = (y & 1) ? 0 : 1;
    const int iy0 = (y + 1 - ky0) >> 1;   // valid if <14
    const int iy1 = iy0 - 1;              // valid if >=0
    const bool v0 = (iy0 < 14), v1 = (iy1 >= 0);
    float acc[28];
    const float bias = b2[c];
    #pragma unroll
    for (int x = 0; x < 28; x++) acc[x] = bias;
    for (int i0 = 0; i0 < 64; i0 += 4) {
      __syncthreads();
      for (int p = tid; p < 2048; p += DEC_T)
        WB2[(p >> 4)*17 + (p & 15)] = w2[i0*512 + p];
      __syncthreads();
      #pragma unroll 1
      for (int ii = 0; ii < 4; ii++) {
        const int i = i0 + ii;
        const float* wr = &WB2[(ii*32 + c)*17];
        float wA[4], wB[4];
        #pragma unroll
        for (int k = 0; k < 4; k++) { wA[k] = wr[ky0*4 + k]; wB[k] = wr[(ky0+2)*4 + k]; }
        const float* Bi = &B1s[i*197];
        float r0[14], r1[14];
        #pragma unroll
        for (int j = 0; j < 14; j++) {
          r0[j] = v0 ? Bi[iy0*14 + j] : 0.0f;
          r1[j] = v1 ? Bi[iy1*14 + j] : 0.0f;
        }
        #pragma unroll
        for (int x = 0; x < 28; x++) {
          const int kxs = (x & 1) ? 0 : 1;
          const int ix0 = (x + 1 - kxs) >> 1;
          const int ix1 = ix0 - 1;
          float s = acc[x];
          if (ix0 < 14) { s = fmaf(r0[ix0], wA[kxs],   s); s = fmaf(r1[ix0], wB[kxs],   s); }
          if (ix1 >= 0) { s = fmaf(r0[ix1], wA[kxs+2], s); s = fmaf(r1[ix1], wB[kxs+2], s); }
          acc[x] = s;
        }
      }
    }
    float* o = &C2s[c*785 + y*28];
    #pragma unroll
    for (int x = 0; x < 28; x++) o[x] = fmaxf(acc[x], 0.0f);
  }
  __syncthreads();

  // ---- conv3: (32,28,28) -> (1,56,56). item = (y=tid>>2, xq=tid&3), 14 px ----
  for (int p = tid; p < 512; p += DEC_T) W3s[p] = w3[p];
  __syncthreads();
  if (tid < 224) {
    const int y = tid >> 2, xq = tid & 3;
    const int x0 = xq * 14;
    const int ky0 = (y & 1) ? 0 : 1;
    const int iy0 = (y + 1 - ky0) >> 1;   // valid if <28
    const int iy1 = iy0 - 1;              // valid if >=0
    const bool v0 = (iy0 < 28), v1 = (iy1 >= 0);
    const int ixb = xq*7 - 1;             // input col for j=0
    float acc[14];
    const float bias = b3[0];
    #pragma unroll
    for (int x = 0; x < 14; x++) acc[x] = bias;
    #pragma unroll 1
    for (int i = 0; i < 32; i++) {
      const float* wr = &W3s[i*16];
      float wA[4], wB[4];
      #pragma unroll
      for (int k = 0; k < 4; k++) { wA[k] = wr[ky0*4 + k]; wB[k] = wr[(ky0+2)*4 + k]; }
      const float* Ci = &C2s[i*785];
      float r0[9], r1[9];
      #pragma unroll
      for (int j = 0; j < 9; j++) {
        const int ix = ixb + j;
        const bool vx = (ix >= 0) && (ix < 28);
        r0[j] = (v0 && vx) ? Ci[iy0*28 + ix] : 0.0f;
        r1[j] = (v1 && vx) ? Ci[iy1*28 + ix] : 0.0f;
      }
      #pragma unroll
      for (int xl = 0; xl < 14; xl++) {
        const int kxs = (xl & 1) ? 0 : 1;       // x = x0+xl, x0 even
        const int j0 = ((xl + 1 - kxs) >> 1) + 1;
        const int j1 = j0 - 1;
        float s = acc[xl];
        s = fmaf(r0[j0], wA[kxs],   s);
        s = fmaf(r1[j0], wB[kxs],   s);
        s = fmaf(r0[j1], wA[kxs+2], s);
        s = fmaf(r1[j1], wB[kxs+2], s);
        acc[xl] = s;
      }
    }
    float* o = &Ds[y*56 + x0];
    #pragma unroll
    for (int xl = 0; xl < 14; xl++) o[xl] = acc[xl];
  }
  __syncthreads();

  // ---- bilinear resize 56->84 (half-pixel, edge clamp == jax renorm) + tanh ----
  for (int p = tid; p < 84*84; p += DEC_T) {
    const int oy = p / 84, ox = p - oy*84;
    const float sy = (oy + 0.5f)*(2.0f/3.0f) - 0.5f;
    const float sx = (ox + 0.5f)*(2.0f/3.0f) - 0.5f;
    const int y0 = (int)floorf(sy), x0i = (int)floorf(sx);
    const float fy = sy - (float)y0, fx = sx - (float)x0i;
    const int y0c = y0 < 0 ? 0 : y0, y1c = (y0 + 1 > 55) ? 55 : (y0 + 1);
    const int x0c = x0i < 0 ? 0 : x0i, x1c = (x0i + 1 > 55) ? 55 : (x0i + 1);
    const float v00 = Ds[y0c*56 + x0c], v01 = Ds[y0c*56 + x1c];
    const float v10 = Ds[y1c*56 + x0c], v11 = Ds[y1c*56 + x1c];
    const float v = (v00*(1.0f - fx) + v01*fx)*(1.0f - fy)
                  + (v10*(1.0f - fx) + v11*fx)*fy;
    out[(size_t)b*7056 + p] = tanhf(v);
  }
}

// ================================ launch ====================================
extern "C" void kernel_launch(void* const* d_in, const int* in_sizes, int n_in,
                              void* d_out, int out_size, void* d_ws, size_t ws_size,
                              hipStream_t stream) {
  (void)in_sizes; (void)n_in; (void)out_size; (void)ws_size;
  const float* z  = (const float*)d_in[0];
  const float* cb = (const float*)d_in[1];
  const float* lw = (const float*)d_in[2];
  const float* lb = (const float*)d_in[3];
  const float* w1 = (const float*)d_in[4];
  const float* b1 = (const float*)d_in[5];
  const float* w2 = (const float*)d_in[6];
  const float* b2 = (const float*)d_in[7];
  const float* w3 = (const float*)d_in[8];
  const float* b3 = (const float*)d_in[9];

  float* out      = (float*)d_out;
  float* out_idx  = out + RECON_N;          // 4096 indices as float
  float* out_loss = out + RECON_N + 4096;   // 2 losses

  char*   ws     = (char*)d_ws;
  double* lpart  = (double*)ws;             // 256 doubles
  int*    idx_ws = (int*)(ws + 2048);       // 4096 ints
  float*  x1     = (float*)(ws + 18432);    // 4096*3136 floats (51.4 MB)

  vq_kernel<<<256, 256, 0, stream>>>(z, cb, idx_ws, out_idx, lpart);
  fin_kernel<<<1, 256, 0, stream>>>(lpart, out_loss);
  linear_kernel<<<dim3(64, 49), 256, 0, stream>>>(cb, idx_ws, lw, lb, x1);

  const int dec_lds = (3136 + 12608 + 25120) * 4;   // 163456 B
  hipFuncSetAttribute((const void*)decoder_kernel,
                      hipFuncAttributeMaxDynamicSharedMemorySize, dec_lds);
  decoder_kernel<<<4096, DEC_T, dec_lds, stream>>>(x1, w1, b1, w2, b2, w3, b3, out);
}

// Round 4
// 2513.915 us; speedup vs baseline: 5.3420x; 1.1687x over previous
//
#include <hip/hip_runtime.h>
#include <math.h>

// Problem constants
#define B_SZ    4096
#define D_DIM   128
#define K_CODES 8192
#define RECON_N (4096*84*84)   // 28901376

// ============================ VQ argmin + losses ============================
// Exact numpy-f32 semantics (verified R2/R3): d2q = fl32(zz - 2r), r = sequential
// f32 FMA chain over d ascending, zz = numpy pairwise-8. Ties -> lowest index.
// R4: 256 blocks x 1024 threads (16 waves/CU vs R3's 4) — R3 was latency-bound
// at 1 wave/SIMD. Waves partition the 128 code-groups; cb read as float4 from
// global (L2-resident, 64B lines consumed immediately); z broadcast from LDS.
__global__ __attribute__((amdgpu_flat_work_group_size(1024,1024),
                          amdgpu_waves_per_eu(4,8)))
void vq_kernel(
    const float* __restrict__ z, const float* __restrict__ cb,
    int* __restrict__ idx_ws, float* __restrict__ out_idx_f,
    double* __restrict__ lpart)
{
  __shared__ float z_s[16][128];
  __shared__ float zz_s[16];
  __shared__ float redv[16][16];   // [wave][row]
  __shared__ int   redi[16][16];
  __shared__ int   win[16];
  __shared__ double wsum[16];
  const int t  = threadIdx.x;
  const int b0 = blockIdx.x * 16;

  for (int p = t; p < 2048; p += 1024) z_s[p >> 7][p & 127] = z[(size_t)b0*128 + p];
  __syncthreads();

  // numpy pairwise-8 emulation of (z*z).sum(axis=1); separate mul/add roundings
  if (t < 16) {
    #pragma clang fp contract(off)
    const float* a = z_s[t];
    float r8[8];
    #pragma unroll
    for (int j = 0; j < 8; j++) { float v = a[j]*a[j]; r8[j] = v; }
    for (int i = 8; i < 128; i += 8) {
      #pragma unroll
      for (int j = 0; j < 8; j++) { float v = a[i+j]*a[i+j]; r8[j] = r8[j] + v; }
    }
    zz_s[t] = ((r8[0]+r8[1]) + (r8[2]+r8[3])) + ((r8[4]+r8[5]) + (r8[6]+r8[7]));
  }
  __syncthreads();

  const int lane = t & 63, wv = t >> 6;
  float zzr[16];
  #pragma unroll
  for (int row = 0; row < 16; row++) zzr[row] = zz_s[row];

  float best[16]; int bid[16];
  #pragma unroll
  for (int row = 0; row < 16; row++) { best[row] = INFINITY; bid[row] = 0; }

  #pragma unroll 1
  for (int k = 0; k < 8; k++) {
    const int cg   = wv + (k << 4);        // 16 waves cover 128 groups of 64 codes
    const int code = (cg << 6) + lane;     // ascending in k for fixed lane
    const float* ep = cb + (size_t)code * 128;
    float r[16];
    #pragma unroll
    for (int row = 0; row < 16; row++) r[row] = 0.0f;
    #pragma unroll 1
    for (int d16 = 0; d16 < 8; d16++) {
      const float4 e0 = *(const float4*)(ep + d16*16 + 0);
      const float4 e1 = *(const float4*)(ep + d16*16 + 4);
      const float4 e2 = *(const float4*)(ep + d16*16 + 8);
      const float4 e3 = *(const float4*)(ep + d16*16 + 12);
      #pragma unroll
      for (int row = 0; row < 16; row++) {
        const float4 z0 = *(const float4*)(&z_s[row][d16*16 + 0]);   // uniform -> broadcast
        const float4 z1 = *(const float4*)(&z_s[row][d16*16 + 4]);
        const float4 z2 = *(const float4*)(&z_s[row][d16*16 + 8]);
        const float4 z3 = *(const float4*)(&z_s[row][d16*16 + 12]);
        float rr = r[row];
        // single dependent FMA chain, d ascending — identical to R3 (bit-exact)
        rr = fmaf(z0.x,e0.x,rr); rr = fmaf(z0.y,e0.y,rr); rr = fmaf(z0.z,e0.z,rr); rr = fmaf(z0.w,e0.w,rr);
        rr = fmaf(z1.x,e1.x,rr); rr = fmaf(z1.y,e1.y,rr); rr = fmaf(z1.z,e1.z,rr); rr = fmaf(z1.w,e1.w,rr);
        rr = fmaf(z2.x,e2.x,rr); rr = fmaf(z2.y,e2.y,rr); rr = fmaf(z2.z,e2.z,rr); rr = fmaf(z2.w,e2.w,rr);
        rr = fmaf(z3.x,e3.x,rr); rr = fmaf(z3.y,e3.y,rr); rr = fmaf(z3.z,e3.z,rr); rr = fmaf(z3.w,e3.w,rr);
        r[row] = rr;
      }
    }
    #pragma unroll
    for (int row = 0; row < 16; row++) {
      const float tt = fmaf(-2.0f, r[row], zzr[row]);  // fl32(zz - 2r), single rounding
      if (tt < best[row]) { best[row] = tt; bid[row] = code; }
    }
  }

  // cross-lane lex argmin per row (tie -> smaller index)
  #pragma unroll 1
  for (int row = 0; row < 16; row++) {
    float v = best[row]; int i = bid[row];
    #pragma unroll
    for (int m = 32; m; m >>= 1) {
      float v2 = __shfl_xor(v, m, 64);
      int   i2 = __shfl_xor(i, m, 64);
      if (v2 < v || (v2 == v && i2 < i)) { v = v2; i = i2; }
    }
    if (lane == 0) { redv[wv][row] = v; redi[wv][row] = i; }
  }
  __syncthreads();

  if (t < 16) {   // row t: reduce over 16 waves
    float v = redv[0][t]; int i = redi[0][t];
    #pragma unroll 1
    for (int w = 1; w < 16; w++) {
      float v2 = redv[w][t]; int i2 = redi[w][t];
      if (v2 < v || (v2 == v && i2 < i)) { v = v2; i = i2; }
    }
    win[t] = i;
    idx_ws[b0 + t] = i;
    out_idx_f[b0 + t] = (float)i;   // float out; exact for idx < 2^24
  }
  __syncthreads();

  // loss partial: sum (z - e_win)^2 over 16 rows (f64; threshold slack huge)
  double ls = 0.0;
  for (int p = t; p < 2048; p += 1024) {
    int r = p >> 7, d = p & 127;
    float diff = z_s[r][d] - cb[(size_t)win[r]*128 + d];
    ls = fma((double)diff, (double)diff, ls);
  }
  #pragma unroll
  for (int m = 32; m; m >>= 1) ls += __shfl_xor(ls, m, 64);
  if (lane == 0) wsum[wv] = ls;
  __syncthreads();
  if (t == 0) {
    double s = 0.0;
    for (int w = 0; w < 16; w++) s += wsum[w];
    lpart[blockIdx.x] = s;
  }
}

__global__ __launch_bounds__(256) void fin_kernel(const double* __restrict__ lpart,
                                                  float* __restrict__ out_loss)
{
  __shared__ double s[256];
  const int t = threadIdx.x;
  s[t] = lpart[t];
  __syncthreads();
  for (int off = 128; off; off >>= 1) {
    if (t < off) s[t] += s[t + off];
    __syncthreads();
  }
  if (t == 0) {
    float l = (float)(s[0] / (4096.0*128.0));
    out_loss[0] = l;   // codebook_loss
    out_loss[1] = l;   // commitment_loss (same value)
  }
}

// ===================== linear: x1[b,o] = cb[idx[b]] . lin_w[o] + lin_b[o] ====
__global__ __launch_bounds__(256) void linear_kernel(
    const float* __restrict__ cb, const int* __restrict__ idx,
    const float* __restrict__ lw, const float* __restrict__ lb,
    float* __restrict__ x1)
{
  __shared__ float As[64][65];
  __shared__ float Bs[64][65];
  __shared__ int idx_s[64];
  const int t  = threadIdx.x;
  const int b0 = blockIdx.x * 64, n0 = blockIdx.y * 64;
  if (t < 64) idx_s[t] = idx[b0 + t];
  float acc[4][4] = {{0.f}};
  const int tr = (t >> 4)*4, tc = (t & 15)*4;
  for (int d0 = 0; d0 < 128; d0 += 64) {
    __syncthreads();
    #pragma unroll
    for (int l = 0; l < 16; l++) {
      int flat = t + l*256;
      int r = flat >> 6, d = flat & 63;
      As[r][d] = cb[(size_t)idx_s[r]*128 + d0 + d];
      Bs[r][d] = lw[(size_t)(n0 + r)*128 + d0 + d];
    }
    __syncthreads();
    #pragma unroll 8
    for (int d = 0; d < 64; d++) {
      float a0 = As[tr+0][d], a1 = As[tr+1][d], a2 = As[tr+2][d], a3 = As[tr+3][d];
      float q0 = Bs[tc+0][d], q1 = Bs[tc+1][d], q2 = Bs[tc+2][d], q3 = Bs[tc+3][d];
      acc[0][0] = fmaf(a0,q0,acc[0][0]); acc[0][1] = fmaf(a0,q1,acc[0][1]);
      acc[0][2] = fmaf(a0,q2,acc[0][2]); acc[0][3] = fmaf(a0,q3,acc[0][3]);
      acc[1][0] = fmaf(a1,q0,acc[1][0]); acc[1][1] = fmaf(a1,q1,acc[1][1]);
      acc[1][2] = fmaf(a1,q2,acc[1][2]); acc[1][3] = fmaf(a1,q3,acc[1][3]);
      acc[2][0] = fmaf(a2,q0,acc[2][0]); acc[2][1] = fmaf(a2,q1,acc[2][1]);
      acc[2][2] = fmaf(a2,q2,acc[2][2]); acc[2][3] = fmaf(a2,q3,acc[2][3]);
      acc[3][0] = fmaf(a3,q0,acc[3][0]); acc[3][1] = fmaf(a3,q1,acc[3][1]);
      acc[3][2] = fmaf(a3,q2,acc[3][2]); acc[3][3] = fmaf(a3,q3,acc[3][3]);
    }
  }
  #pragma unroll
  for (int i = 0; i < 4; i++)
    #pragma unroll
    for (int j = 0; j < 4; j++)
      x1[(size_t)(b0 + tr + i)*3136 + n0 + tc + j] = acc[i][j] + lb[n0 + tc + j];
}

// ===================== decoder_a: conv1 + conv2 per image ====================
// LDS = only B1s, halo-padded: 64 ch x (16 rows x 16 cols + 4 pad) = 16640 f
// = 65 KB -> 2 blocks/CU (28 waves). Weights & x1 from global (L1/L2-hot).
// Halo (zeroed borders) removes every boundary cndmask in conv2 and makes the
// row reads ds_read_b128. conv2 split into two x-half passes: live set
// acc[14]+r0[9]+r1[9]+w[8] ~= 50 VGPR, so the waves_per_eu(7) pin (V<=72) holds.
#define DA_T 896
#define B1_CS 260   // channel stride: %32==4 -> 8-way write conflicts only on epilogue
__global__ __attribute__((amdgpu_flat_work_group_size(DA_T, DA_T),
                          amdgpu_waves_per_eu(7, 8)))
void decoder_a(
    const float* __restrict__ x1,
    const float* __restrict__ w1, const float* __restrict__ b1,
    const float* __restrict__ w2, const float* __restrict__ b2,
    float* __restrict__ a2, int b_off)
{
  extern __shared__ float B1s[];   // 64*260 = 16640 floats
  const int tid = threadIdx.x;
  const int b   = blockIdx.x;        // local index into a2 chunk buffer
  const int bg  = b + b_off;         // global image index

  for (int p = tid; p < 64*B1_CS; p += DA_T) B1s[p] = 0.0f;
  __syncthreads();

  // ---- conv1: (64,7,7) -> (64,14,14), relu. item = (c=tid&63, y=tid>>6) ----
  {
    const int c = tid & 63, y = tid >> 6;
    const int ky0 = (y & 1) ? 0 : 1;
    const int iy0 = (y + 1 - ky0) >> 1;   // valid if <7
    const int iy1 = iy0 - 1;              // valid if >=0
    const bool v0 = (iy0 < 7), v1 = (iy1 >= 0);   // wave-uniform (y = wave idx)
    float acc[14];
    const float bias = b1[c];
    #pragma unroll
    for (int x = 0; x < 14; x++) acc[x] = bias;
    const float* xim = x1 + (size_t)bg*3136;
    #pragma unroll 1
    for (int i = 0; i < 64; i++) {
      const float* wp = w1 + (((i << 6) + c) << 4) + ky0*4;
      const float4 wA4 = *(const float4*)(wp);
      const float4 wB4 = *(const float4*)(wp + 8);
      const float wa[4] = {wA4.x, wA4.y, wA4.z, wA4.w};
      const float wb[4] = {wB4.x, wB4.y, wB4.z, wB4.w};
      float r0[7], r1[7];
      if (v0) {
        const float* xr = xim + i*49 + iy0*7;
        #pragma unroll
        for (int j = 0; j < 7; j++) r0[j] = xr[j];
      } else {
        #pragma unroll
        for (int j = 0; j < 7; j++) r0[j] = 0.0f;
      }
      if (v1) {
        const float* xr = xim + i*49 + iy1*7;
        #pragma unroll
        for (int j = 0; j < 7; j++) r1[j] = xr[j];
      } else {
        #pragma unroll
        for (int j = 0; j < 7; j++) r1[j] = 0.0f;
      }
      #pragma unroll
      for (int x = 0; x < 14; x++) {
        const int kxs = (x & 1) ? 0 : 1;
        const int ix0 = (x + 1 - kxs) >> 1;
        const int ix1 = ix0 - 1;
        float s = acc[x];
        if (ix0 < 7)  { s = fmaf(r0[ix0], wa[kxs],   s); s = fmaf(r1[ix0], wb[kxs],   s); }
        if (ix1 >= 0) { s = fmaf(r0[ix1], wa[kxs+2], s); s = fmaf(r1[ix1], wb[kxs+2], s); }
        acc[x] = s;
      }
    }
    // write interior of halo plane: row y+1, cols 1..14
    float* o = &B1s[c*B1_CS + (y + 1)*16 + 1];
    #pragma unroll
    for (int x = 0; x < 14; x++) o[x] = fmaxf(acc[x], 0.0f);
  }
  __syncthreads();

  // ---- conv2: (64,14,14) -> (32,28,28), relu. item = (c=tid&31, y=tid>>5) ----
  {
    const int c = tid & 31, y = tid >> 5;
    const int ky0 = (y & 1) ? 0 : 1;
    const int iy0 = (y + 1 - ky0) >> 1;     // 0..14
    const int row0 = iy0 + 1;               // halo row for ky0   (1..15)
    const int row1 = iy0;                   // halo row for ky0+2 (0..14)
    const float bias = b2[c];
    float* a2p = a2 + (size_t)b*25088 + c*784 + y*28;
    #pragma unroll
    for (int pass = 0; pass < 2; pass++) {
      const int cbase = pass*7;             // r[j] = halo col cbase+j, j=0..8
      float acc[14];
      #pragma unroll
      for (int x = 0; x < 14; x++) acc[x] = bias;
      #pragma unroll 1
      for (int i = 0; i < 64; i++) {
        const float* wp = w2 + (((i << 5) + c) << 4) + ky0*4;
        const float4 wA4 = *(const float4*)(wp);
        const float4 wB4 = *(const float4*)(wp + 8);
        const float wa[4] = {wA4.x, wA4.y, wA4.z, wA4.w};
        const float wb[4] = {wB4.x, wB4.y, wB4.z, wB4.w};
        const float* rp0 = &B1s[i*B1_CS + row0*16];
        const float* rp1 = &B1s[i*B1_CS + row1*16];
        float r0[9], r1[9];
        if (pass == 0) {   // cols 0..8: b128@0, b128@4, scalar@8
          const float4 a = *(const float4*)(rp0 + 0);
          const float4 bq = *(const float4*)(rp0 + 4);
          r0[0]=a.x; r0[1]=a.y; r0[2]=a.z; r0[3]=a.w;
          r0[4]=bq.x; r0[5]=bq.y; r0[6]=bq.z; r0[7]=bq.w; r0[8]=rp0[8];
          const float4 c4 = *(const float4*)(rp1 + 0);
          const float4 d4 = *(const float4*)(rp1 + 4);
          r1[0]=c4.x; r1[1]=c4.y; r1[2]=c4.z; r1[3]=c4.w;
          r1[4]=d4.x; r1[5]=d4.y; r1[6]=d4.z; r1[7]=d4.w; r1[8]=rp1[8];
        } else {           // cols 7..15: scalar@7, b128@8, b128@12
          r0[0]=rp0[7];
          const float4 a = *(const float4*)(rp0 + 8);
          const float4 bq = *(const float4*)(rp0 + 12);
          r0[1]=a.x; r0[2]=a.y; r0[3]=a.z; r0[4]=a.w;
          r0[5]=bq.x; r0[6]=bq.y; r0[7]=bq.z; r0[8]=bq.w;
          r1[0]=rp1[7];
          const float4 c4 = *(const float4*)(rp1 + 8);
          const float4 d4 = *(const float4*)(rp1 + 12);
          r1[1]=c4.x; r1[2]=c4.y; r1[3]=c4.z; r1[4]=c4.w;
          r1[5]=d4.x; r1[6]=d4.y; r1[7]=d4.z; r1[8]=d4.w;
        }
        #pragma unroll
        for (int xl = 0; xl < 14; xl++) {
          const int x = pass*14 + xl;
          const int kxs = (xl & 1) ? 0 : 1;       // x parity == xl parity
          const int j = ((x + 1 - kxs) >> 1) + 1 - cbase;   // 1..8
          float s = acc[xl];
          s = fmaf(r0[j],   wa[kxs],   s);
          s = fmaf(r1[j],   wb[kxs],   s);
          s = fmaf(r0[j-1], wa[kxs+2], s);
          s = fmaf(r1[j-1], wb[kxs+2], s);
          acc[xl] = s;
        }
      }
      #pragma unroll
      for (int xl = 0; xl < 14; xl++) acc[xl] = fmaxf(acc[xl], 0.0f);
      float* st = a2p + pass*14;
      if (pass == 0) {
        *(float4*)(st + 0)  = make_float4(acc[0],acc[1],acc[2],acc[3]);
        *(float4*)(st + 4)  = make_float4(acc[4],acc[5],acc[6],acc[7]);
        *(float4*)(st + 8)  = make_float4(acc[8],acc[9],acc[10],acc[11]);
        *(float2*)(st + 12) = make_float2(acc[12],acc[13]);
      } else {
        *(float2*)(st + 0)  = make_float2(acc[0],acc[1]);
        *(float4*)(st + 2)  = make_float4(acc[2],acc[3],acc[4],acc[5]);
        *(float4*)(st + 6)  = make_float4(acc[6],acc[7],acc[8],acc[9]);
        *(float4*)(st + 10) = make_float4(acc[10],acc[11],acc[12],acc[13]);
      }
    }
  }
}

// ============ decoder_b: conv3 + bilinear resize 56->84 + tanh ==============
#define DB_T 896
__global__ __attribute__((amdgpu_flat_work_group_size(DB_T, DB_T)))
void decoder_b(
    const float* __restrict__ a2,
    const float* __restrict__ w3, const float* __restrict__ b3,
    float* __restrict__ out, int b_off)
{
  extern __shared__ float lds[];
  float* Cs  = lds;           // 25088 (a2 image, [c][y][x])
  float* Ds  = lds + 25088;   // 3136  (conv3 out, 56x56)
  float* W3s = lds + 28224;   // 512
  const int tid = threadIdx.x;
  const int b   = blockIdx.x;
  const int bg  = b + b_off;

  {
    const float4* src = (const float4*)(a2 + (size_t)b*25088);
    for (int p = tid; p < 6272; p += DB_T) ((float4*)Cs)[p] = src[p];
    for (int p = tid; p < 512; p += DB_T) W3s[p] = w3[p];
  }
  __syncthreads();

  if (tid < 784) {   // item = (y=tid/14 in 0..55, xq=tid%14), 4 px each
    const int y = tid / 14, xq = tid - y*14;
    const int x0 = xq * 4;
    const int ky0 = (y & 1) ? 0 : 1;
    const int iy0 = (y + 1 - ky0) >> 1;   // valid if <28
    const int iy1 = iy0 - 1;              // valid if >=0
    const bool v0 = (iy0 < 28), v1 = (iy1 >= 0);
    const int ixb = (x0 >> 1) - 1;        // input col for j=0
    float acc[4];
    const float bias = b3[0];
    #pragma unroll
    for (int x = 0; x < 4; x++) acc[x] = bias;
    #pragma unroll 1
    for (int i = 0; i < 32; i++) {
      const float* wr = &W3s[i*16 + ky0*4];
      float wa[4], wb[4];
      #pragma unroll
      for (int k = 0; k < 4; k++) { wa[k] = wr[k]; wb[k] = wr[8 + k]; }
      const float* Ci = &Cs[i*784];
      float r0[4], r1[4];
      #pragma unroll
      for (int j = 0; j < 4; j++) {
        const int ix = ixb + j;
        const bool vx = (ix >= 0) && (ix < 28);
        r0[j] = (v0 && vx) ? Ci[iy0*28 + ix] : 0.0f;
        r1[j] = (v1 && vx) ? Ci[iy1*28 + ix] : 0.0f;
      }
      #pragma unroll
      for (int xl = 0; xl < 4; xl++) {
        const int kxs = (xl & 1) ? 0 : 1;     // x0 even
        const int j = ((x0 + xl + 1 - kxs) >> 1) - ixb;   // 1..3
        float s = acc[xl];
        s = fmaf(r0[j],   wa[kxs],   s);
        s = fmaf(r1[j],   wb[kxs],   s);
        s = fmaf(r0[j-1], wa[kxs+2], s);
        s = fmaf(r1[j-1], wb[kxs+2], s);
        acc[xl] = s;
      }
    }
    *(float4*)(&Ds[y*56 + x0]) = make_float4(acc[0],acc[1],acc[2],acc[3]);
  }
  __syncthreads();

  // bilinear resize 56->84 (half-pixel, edge clamp == jax renorm) + tanh
  for (int p = tid; p < 84*84; p += DB_T) {
    const int oy = p / 84, ox = p - oy*84;
    const float sy = (oy + 0.5f)*(2.0f/3.0f) - 0.5f;
    const float sx = (ox + 0.5f)*(2.0f/3.0f) - 0.5f;
    const int y0 = (int)floorf(sy), x0i = (int)floorf(sx);
    const float fy = sy - (float)y0, fx = sx - (float)x0i;
    const int y0c = y0 < 0 ? 0 : y0, y1c = (y0 + 1 > 55) ? 55 : (y0 + 1);
    const int x0c = x0i < 0 ? 0 : x0i, x1c = (x0i + 1 > 55) ? 55 : (x0i + 1);
    const float v00 = Ds[y0c*56 + x0c], v01 = Ds[y0c*56 + x1c];
    const float v10 = Ds[y1c*56 + x0c], v11 = Ds[y1c*56 + x1c];
    const float v = (v00*(1.0f - fx) + v01*fx)*(1.0f - fy)
                  + (v10*(1.0f - fx) + v11*fx)*fy;
    out[(size_t)bg*7056 + p] = tanhf(v);
  }
}

// ================================ launch ====================================
extern "C" void kernel_launch(void* const* d_in, const int* in_sizes, int n_in,
                              void* d_out, int out_size, void* d_ws, size_t ws_size,
                              hipStream_t stream) {
  (void)in_sizes; (void)n_in; (void)out_size;
  const float* z  = (const float*)d_in[0];
  const float* cb = (const float*)d_in[1];
  const float* lw = (const float*)d_in[2];
  const float* lb = (const float*)d_in[3];
  const float* w1 = (const float*)d_in[4];
  const float* b1 = (const float*)d_in[5];
  const float* w2 = (const float*)d_in[6];
  const float* b2 = (const float*)d_in[7];
  const float* w3 = (const float*)d_in[8];
  const float* b3 = (const float*)d_in[9];

  float* out      = (float*)d_out;
  float* out_idx  = out + RECON_N;          // 4096 indices as float
  float* out_loss = out + RECON_N + 4096;   // 2 losses

  char*   ws     = (char*)d_ws;
  double* lpart  = (double*)ws;             // 256 doubles
  int*    idx_ws = (int*)(ws + 4096);       // 4096 ints
  float*  x1     = (float*)(ws + 32768);    // 4096*3136 floats (51.4 MB)
  const size_t a2_off = 32768 + (size_t)4096*3136*4;
  float*  a2     = (float*)(ws + a2_off);   // up to 4096*25088 floats (411 MB)

  // chunk the decoder if ws is too small for the full a2 buffer
  long long avail = (long long)ws_size - (long long)a2_off;
  int cap = (int)(avail / (25088*4));
  if (cap > 4096) cap = 4096;
  if (cap < 1) cap = 1;   // (ws smaller than R3's needs would have failed already)

  vq_kernel<<<256, 1024, 0, stream>>>(z, cb, idx_ws, out_idx, lpart);
  fin_kernel<<<1, 256, 0, stream>>>(lpart, out_loss);
  linear_kernel<<<dim3(64, 49), 256, 0, stream>>>(cb, idx_ws, lw, lb, x1);

  const int da_lds = 64*B1_CS*4;           // 66560 B -> 2 blocks/CU
  const int db_lds = (25088+3136+512)*4;   // 114944 B
  hipFuncSetAttribute((const void*)decoder_a,
                      hipFuncAttributeMaxDynamicSharedMemorySize, da_lds);
  hipFuncSetAttribute((const void*)decoder_b,
                      hipFuncAttributeMaxDynamicSharedMemorySize, db_lds);
  for (int b0 = 0; b0 < B_SZ; b0 += cap) {
    const int n = (B_SZ - b0 < cap) ? (B_SZ - b0) : cap;
    decoder_a<<<n, DA_T, da_lds, stream>>>(x1, w1, b1, w2, b2, a2, b0);
    decoder_b<<<n, DB_T, db_lds, stream>>>(a2, w3, b3, out, b0);
  }
}